// Round 5
// baseline (830.180 us; speedup 1.0000x reference)
//
#include <hip/hip_runtime.h>
#include <stdint.h>

typedef __bf16 bf16x8 __attribute__((ext_vector_type(8)));
typedef float f32x4v __attribute__((ext_vector_type(4)));

typedef __attribute__((address_space(1))) const void gconst_t;
typedef __attribute__((address_space(3))) void lds_t;

// global -> LDS direct copy, 16 B per lane. LDS dest = wave-uniform base + lane*16.
#define GLL16(gp, sp) __builtin_amdgcn_global_load_lds((gconst_t*)(uintptr_t)(gp), (lds_t*)(uintptr_t)(sp), 16, 0, 0)

__device__ __forceinline__ unsigned short f2bf(float f) {
  unsigned int u = __float_as_uint(f);
  u = (u + 0x7FFFu + ((u >> 16) & 1u)) >> 16;
  return (unsigned short)u;
}
__device__ __forceinline__ float bf2f(unsigned int b) {
  return __uint_as_float(b << 16);
}

// ---------------- sizes ----------------
// x: (64,512,32,32) f32. padded NHWC: [n][34][34][512] bf16
#define SPP 1156  // 34*34

// ---------------- bn param prep ----------------
__global__ __launch_bounds__(512) void bnprep(
    const float* __restrict__ g1, const float* __restrict__ b1,
    const float* __restrict__ m1, const float* __restrict__ v1,
    const float* __restrict__ g2, const float* __restrict__ b2,
    const float* __restrict__ m2, const float* __restrict__ v2,
    float* __restrict__ bnp) {
  int t = threadIdx.x;
  float i1 = g1[t] * rsqrtf(v1[t] + 1e-5f);
  bnp[t] = i1;
  bnp[512 + t] = b1[t] - m1[t] * i1;
  float i2 = g2[t] * rsqrtf(v2[t] + 1e-5f);
  bnp[1024 + t] = i2;
  bnp[1536 + t] = b2[t] - m2[t] * i2;
}

// ---------------- pad-ring zero for Ap and Hp (interiors are fully overwritten) ----------------
__global__ __launch_bounds__(256) void ring_zero(unsigned short* __restrict__ Ap,
                                                 unsigned short* __restrict__ Hp) {
  const int n = blockIdx.y;
  const int p = blockIdx.x * 4 + (threadIdx.x >> 6);  // 0..131 ring pixel
  const int lane = threadIdx.x & 63;
  int y, x;
  if (p < 34) { y = 0; x = p; }
  else if (p < 68) { y = 33; x = p - 34; }
  else if (p < 100) { y = p - 67; x = 0; }
  else { y = p - 99; x = 33; }
  const uint4 z = {0u, 0u, 0u, 0u};
  const size_t off = ((size_t)((n * 34 + y) * 34 + x)) * 512 + lane * 8;
  *(uint4*)(Ap + off) = z;
  *(uint4*)(Hp + off) = z;
}

// ---------------- weight transform: w[co][ci][dy][dx] f32 -> wt[tap][co][ci] bf16 ----------------
__global__ __launch_bounds__(256) void wtrans(const float* __restrict__ w1, const float* __restrict__ w2,
                                              unsigned short* __restrict__ w1t, unsigned short* __restrict__ w2t) {
  unsigned e = blockIdx.x * 256u + threadIdx.x;
  if (e >= 4718592u) return;
  const float* w = (e < 2359296u) ? w1 : w2;
  unsigned short* o = (e < 2359296u) ? w1t : w2t;
  unsigned r = (e < 2359296u) ? e : (e - 2359296u);
  unsigned ci = r & 511u, co = (r >> 9) & 511u, tt = r >> 18;
  o[r] = f2bf(w[(co * 512u + ci) * 9u + tt]);
}

// ---------------- bn1+relu, write padded NHWC bf16, per-(n,ci,yblk) partial sums ----------------
__global__ __launch_bounds__(256) void bn1_relu_stage(const float* __restrict__ x, const float* __restrict__ bnp,
                                                      unsigned short* __restrict__ Ap, float* __restrict__ partial) {
  int bid = blockIdx.x;
  int n = bid >> 6, ciblk = (bid >> 3) & 7, yblk = bid & 7;
  int ci0 = ciblk * 64, y0 = yblk * 4;
  int t = threadIdx.x;
  __shared__ __align__(16) float vals[64 * 128];
  __shared__ float ivs[64], bbs[64];
  if (t < 64) { ivs[t] = bnp[ci0 + t]; bbs[t] = bnp[512 + ci0 + t]; }
  __syncthreads();
#pragma unroll
  for (int i = 0; i < 8; ++i) {
    int f4 = i * 256 + t;
    int cil = f4 >> 5, xq = f4 & 31;
    const float* src = x + ((size_t)(n * 512 + ci0 + cil)) * 1024 + y0 * 32 + xq * 4;
    f32x4v v = *(const f32x4v*)src;
    float iv = ivs[cil], bb = bbs[cil];
    f32x4v r;
    r[0] = fmaxf(fmaf(v[0], iv, bb), 0.f);
    r[1] = fmaxf(fmaf(v[1], iv, bb), 0.f);
    r[2] = fmaxf(fmaf(v[2], iv, bb), 0.f);
    r[3] = fmaxf(fmaf(v[3], iv, bb), 0.f);
    *(f32x4v*)&vals[cil * 128 + xq * 4] = r;
  }
  __syncthreads();
  // partial sums per ci (deterministic)
  {
    int cil = t >> 2, q = t & 3;
    float s = 0.f;
#pragma unroll
    for (int j = 0; j < 32; ++j) s += vals[cil * 128 + q * 32 + j];
    s += __shfl_xor(s, 1);
    s += __shfl_xor(s, 2);
    if (q == 0) partial[((size_t)n * 512 + ci0 + cil) * 8 + yblk] = s;
  }
  // transpose to padded NHWC bf16
  {
    int yx = t >> 1, half = t & 1;
    int y = y0 + (yx >> 5), xx = yx & 31;
    unsigned short* dp = Ap + ((size_t)((n * 34 + y + 1) * 34 + (xx + 1))) * 512 + ci0 + half * 32;
    unsigned wrd[16];
#pragma unroll
    for (int j = 0; j < 16; ++j) {
      unsigned lo = f2bf(vals[(half * 32 + 2 * j) * 128 + yx]);
      unsigned hi = f2bf(vals[(half * 32 + 2 * j + 1) * 128 + yx]);
      wrd[j] = lo | (hi << 16);
    }
#pragma unroll
    for (int k = 0; k < 4; ++k) {
      uint4 u;
      u.x = wrd[k * 4]; u.y = wrd[k * 4 + 1]; u.z = wrd[k * 4 + 2]; u.w = wrd[k * 4 + 3];
      *(uint4*)(dp + k * 8) = u;
    }
  }
}

// ---------------- probe + analytic mask; writes pred_probe ----------------
__global__ __launch_bounds__(256) void probe_mask(const float* __restrict__ partial,
                                                  const float* __restrict__ fc1w, const float* __restrict__ fc1b,
                                                  const float* __restrict__ fc2w, const float* __restrict__ fc2b,
                                                  float* __restrict__ maskp, float* __restrict__ probeout) {
  int n = blockIdx.x, t = threadIdx.x;
  int lane = t & 63, wv = t >> 6;
  __shared__ float gl[512], sl[512], zl[240], hl[240], dzl[240], logl[10], red[4];
  __shared__ int idx2[2];
  for (int c = t; c < 512; c += 256) {
    const float* pp = partial + ((size_t)n * 512 + c) * 8;
    float s = 0.f;
#pragma unroll
    for (int j = 0; j < 8; ++j) s += pp[j];
    gl[c] = s * (1.f / 1024.f);
  }
  __syncthreads();
  if (t < 240) {
    float z = fc1b[t];
    const float* wr = fc1w + t * 512;
    for (int c = 0; c < 512; ++c) z = fmaf(gl[c], wr[c], z);
    zl[t] = z;
    float u = 5.f * z;
    float sp = (u > 20.f) ? u : log1pf(expf(u));
    hl[t] = sp * 0.2f;
  }
  __syncthreads();
  if (t < 10) {
    float L = fc2b[t];
    const float* wr = fc2w + t * 240;
    for (int h = 0; h < 240; ++h) L = fmaf(hl[h], wr[h], L);
    logl[t] = L;
    probeout[n * 10 + t] = L;
  }
  __syncthreads();
  if (t == 0) {
    float b1v = -1e30f, b2v = -1e30f; int i1 = 0, i2 = 0;
    for (int j = 0; j < 10; ++j) {
      float v = logl[j];
      if (v > b1v) { b2v = b1v; i2 = i1; b1v = v; i1 = j; }
      else if (v > b2v) { b2v = v; i2 = j; }
    }
    idx2[0] = i1; idx2[1] = i2;
  }
  __syncthreads();
  if (t < 240) {
    float dh = fc2w[idx2[0] * 240 + t] + fc2w[idx2[1] * 240 + t];
    float u = 5.f * zl[t];
    float sg = 1.f / (1.f + expf(-u));
    dzl[t] = dh * sg;
  }
  __syncthreads();
  for (int c = t; c < 512; c += 256) {
    float s = 0.f;
    for (int h = 0; h < 240; ++h) s = fmaf(dzl[h], fc1w[h * 512 + c], s);
    sl[c] = s;
  }
  __syncthreads();
  float m = fmaxf(sl[t], sl[t + 256]);
#pragma unroll
  for (int o = 32; o > 0; o >>= 1) m = fmaxf(m, __shfl_xor(m, o));
  if (lane == 0) red[wv] = m;
  __syncthreads();
  float mx = fmaxf(fmaxf(red[0], red[1]), fmaxf(red[2], red[3]));
  float e0 = expf(sl[t] - mx), e1 = expf(sl[t + 256] - mx);
  float sum = e0 + e1;
#pragma unroll
  for (int o = 32; o > 0; o >>= 1) sum += __shfl_xor(sum, o);
  __syncthreads();
  if (lane == 0) red[wv] = sum;
  __syncthreads();
  float inv = 2.f / (red[0] + red[1] + red[2] + red[3]);
  maskp[(size_t)n * 512 + t] = e0 * inv;
  maskp[(size_t)n * 512 + t + 256] = e1 * inv;
}

// ---------------- in-place mask multiply on padded NHWC bf16 ----------------
__global__ __launch_bounds__(256) void apply_mask(unsigned short* __restrict__ Ap, const float* __restrict__ maskp) {
  int n = blockIdx.y;
  size_t off = (size_t)n * (SPP * 512) + (size_t)blockIdx.x * 2048 + threadIdx.x * 8;
  int ci0 = (int)(threadIdx.x * 8) & 511;
  uint4 v = *(uint4*)(Ap + off);
  const float* mp = maskp + n * 512 + ci0;
  unsigned r0, r1;
  r0 = f2bf(bf2f(v.x & 0xFFFFu) * mp[0]); r1 = f2bf(bf2f(v.x >> 16) * mp[1]); v.x = r0 | (r1 << 16);
  r0 = f2bf(bf2f(v.y & 0xFFFFu) * mp[2]); r1 = f2bf(bf2f(v.y >> 16) * mp[3]); v.y = r0 | (r1 << 16);
  r0 = f2bf(bf2f(v.z & 0xFFFFu) * mp[4]); r1 = f2bf(bf2f(v.z >> 16) * mp[5]); v.z = r0 | (r1 << 16);
  r0 = f2bf(bf2f(v.w & 0xFFFFu) * mp[6]); r1 = f2bf(bf2f(v.w >> 16) * mp[7]); v.w = r0 | (r1 << 16);
  *(uint4*)(Ap + off) = v;
}

// ================= 256x128 implicit-GEMM conv, tap-reuse A panel, 2 blocks/CU (v3) =================
// BM=256 px, BN=128 co, BK=64. 8 waves (2M x 4N: each wave 128px x 32co), 512 thr.
// LDS = A panel 48K [384 slots][128B] + B dbuf 2x16K = 81920 B exactly -> 2 blocks/CU.
// K order: k8 outer (8) x tap inner (9); ts = k8*9+tap; B buf = ts&1 = (k8+tap)&1
// (compile-time via k8-pair unroll, PAR = k8&1). B prefetch distance 1 (tile ts+1
// staged during ts; drained by VM0 at ts end — issue-to-wait >= 1500 cyc, L2-resident).
// Swizzle (both-sides, rule 21): LDS chunk q of slot/row s holds global chunk q^(s&7)
// (linear GLL dest + permuted source); reads XOR back. kq = (t&7)^((t>>3)&7) is
// round-invariant for both A panel and B tiles -> single base reg each.
// Phases per tap-step: ph1 {RD_A(0) 8ds, RD_B 4ds, ST_B(ts+1) 2GLL; BARR; LGKM0;
// 16 MFMA; BARR}  ph2 {RD_A(1) 8ds; BARR; LGKM0; 16 MFMA; VM0; BARR}.
// tap8 ph2 splits its MFMA around ST_A3 (6 GLL, next k8's panel; issued >=1 barrier
// after panel's last drained read) and the VM0 drains A+B before next k8 reads.
#define LT(M) ((l4 ^ (((M) + l7) & 7)) << 4)

#define RD_A(QM, TAP) do {                                                    \
  const int _S0 = ((QM) * 2 + (TAP) / 3) * 34 + (TAP) % 3;                    \
  const int _l0 = l15x128 + LT(_S0 & 7);                                      \
  const int _l1 = l15x128 + LT((_S0 + 4) & 7);                                \
  const char* _p0 = ldsAW + _S0 * 128;                                        \
  const char* _p1 = _p0 + 8704;                                               \
  a[0][0] = *(const bf16x8*)(_p0 + _l0);                                      \
  a[0][1] = *(const bf16x8*)(_p0 + (_l0 ^ 64));                               \
  a[1][0] = *(const bf16x8*)(_p0 + 2048 + _l0);                               \
  a[1][1] = *(const bf16x8*)(_p0 + 2048 + (_l0 ^ 64));                        \
  a[2][0] = *(const bf16x8*)(_p1 + _l1);                                      \
  a[2][1] = *(const bf16x8*)(_p1 + (_l1 ^ 64));                               \
  a[3][0] = *(const bf16x8*)(_p1 + 2048 + _l1);                               \
  a[3][1] = *(const bf16x8*)(_p1 + 2048 + (_l1 ^ 64));                        \
} while (0)

#define RD_B(BUF) do {                                                        \
  const char* _pb = ldsb + 49152 + (BUF) * 16384 + bRdC;                      \
  b[0][0] = *(const bf16x8*)(_pb);                                            \
  b[0][1] = *(const bf16x8*)(ldsb + 49152 + (BUF) * 16384 + (bRdC ^ 64));     \
  b[1][0] = *(const bf16x8*)(_pb + 2048);                                     \
  b[1][1] = *(const bf16x8*)(ldsb + 49152 + (BUF) * 16384 + (bRdC ^ 64) + 2048); \
} while (0)

#define ST_B(BUF, BP) do {                                                    \
  GLL16((BP) + bOff0,         ldsb + 49152 + (BUF) * 16384 + tb);             \
  GLL16((BP) + bOff0 + 32768, ldsb + 49152 + (BUF) * 16384 + 8192 + tb);      \
} while (0)

#define ST_A3(AP) do {                                                        \
  GLL16((AP) + aOff0,          ldsb + tb);                                    \
  GLL16((AP) + aOff0 + 32768,  ldsb + 8192 + tb);                             \
  GLL16((AP) + aOff0 + 65536,  ldsb + 16384 + tb);                            \
  GLL16((AP) + aOff0 + 98304,  ldsb + 24576 + tb);                            \
  GLL16((AP) + aOff0 + 131072, ldsb + 32768 + tb);                            \
  GLL16((AP) + aOff0 + 163840, ldsb + 40960 + tb);                            \
} while (0)

#define MFMA_H(QM) do {                                                       \
  _Pragma("unroll") for (int mi = 0; mi < 4; ++mi)                            \
  _Pragma("unroll") for (int ni = 0; ni < 2; ++ni) {                          \
    acc[QM][mi][ni] = __builtin_amdgcn_mfma_f32_16x16x32_bf16(                \
        a[mi][0], b[ni][0], acc[QM][mi][ni], 0, 0, 0);                        \
    acc[QM][mi][ni] = __builtin_amdgcn_mfma_f32_16x16x32_bf16(                \
        a[mi][1], b[ni][1], acc[QM][mi][ni], 0, 0, 0); }                      \
} while (0)

#define MFMA_HN(QM, NI) do {                                                  \
  _Pragma("unroll") for (int mi = 0; mi < 4; ++mi) {                          \
    acc[QM][mi][NI] = __builtin_amdgcn_mfma_f32_16x16x32_bf16(                \
        a[mi][0], b[NI][0], acc[QM][mi][NI], 0, 0, 0);                        \
    acc[QM][mi][NI] = __builtin_amdgcn_mfma_f32_16x16x32_bf16(                \
        a[mi][1], b[NI][1], acc[QM][mi][NI], 0, 0, 0); }                      \
} while (0)

#define BARR __builtin_amdgcn_s_barrier()
#define LGKM0 do { asm volatile("s_waitcnt lgkmcnt(0)" ::: "memory");         \
                   __builtin_amdgcn_sched_barrier(0); } while (0)
#define VM0 asm volatile("s_waitcnt vmcnt(0)" ::: "memory")
#define PRIO1 __builtin_amdgcn_s_setprio(1)
#define PRIO0 __builtin_amdgcn_s_setprio(0)

#define TAPSTEP(TAP, PAR) do {                                                \
  const unsigned short* _bpn;                                                 \
  if ((TAP) < 8) _bpn = Wt + (size_t)((TAP) + 1) * 262144 + k8 * 64;          \
  else           _bpn = (k8 < 7) ? Wt + (size_t)(k8 + 1) * 64                 \
                                 : Wt + (size_t)8 * 262144 + 7 * 64;          \
  /* ph1 */                                                                   \
  RD_A(0, TAP); RD_B(((TAP) + (PAR)) & 1);                                    \
  ST_B((((TAP) + (PAR)) & 1) ^ 1, _bpn);                                      \
  BARR; LGKM0;                                                                \
  PRIO1; MFMA_H(0); PRIO0;                                                    \
  BARR;                                                                       \
  /* ph2 */                                                                   \
  RD_A(1, TAP);                                                               \
  BARR; LGKM0;                                                                \
  if ((TAP) < 8) {                                                            \
    PRIO1; MFMA_H(1); PRIO0;                                                  \
    VM0; BARR;                                                                \
  } else {                                                                    \
    PRIO1; MFMA_HN(1, 0); PRIO0;                                              \
    BARR;                                                                     \
    if (k8 < 7) { ST_A3(Ag + (size_t)(k8 + 1) * 64); }                        \
    BARR;                                                                     \
    PRIO1; MFMA_HN(1, 1); PRIO0;                                              \
    VM0; BARR;                                                                \
  }                                                                           \
} while (0)

#define TAP9(PAR)                                                             \
  TAPSTEP(0, PAR); TAPSTEP(1, PAR); TAPSTEP(2, PAR);                          \
  TAPSTEP(3, PAR); TAPSTEP(4, PAR); TAPSTEP(5, PAR);                          \
  TAPSTEP(6, PAR); TAPSTEP(7, PAR); TAPSTEP(8, PAR);

template <int MODE>
__global__ __launch_bounds__(512, 4) void conv256(
    const unsigned short* __restrict__ Ain,
    const unsigned short* __restrict__ Wt,
    const float* __restrict__ bnp,
    unsigned short* __restrict__ Hout,
    const float* __restrict__ xres,
    float* __restrict__ outp) {
  __shared__ __align__(16) char ldsb[81920];  // A panel 48K + B dbuf 32K

  const int t = threadIdx.x;
  const int lane = t & 63;
  const int wv = t >> 6;
  const int wm = wv >> 2;  // 0..1: M-half (128 px)
  const int wn = wv & 3;   // 0..3: N quarter (32 co)

  const int bid = blockIdx.x;
  const int logical = (bid & 7) * 128 + (bid >> 3);  // bijective: 1024 % 8 == 0
  const int nt = logical & 3, mt = logical >> 2;
  const int n = mt >> 2, yblk = mt & 3;
  const int co0 = nt * 128;

  const unsigned short* Ag = Ain + (size_t)n * (SPP * 512);

  // round-invariant source swizzle chunk: kq = (t&7) ^ ((t>>3)&7)
  const int kq8 = ((t & 7) ^ ((t >> 3) & 7)) * 8;
  const int aOff0 = (yblk * 272 + (t >> 3)) * 512 + kq8;
  const int bOff0 = (co0 + (t >> 3)) * 512 + kq8;
  const int tb = t * 16;
  const int l4 = lane >> 4, l7 = lane & 7;
  const int l15x128 = (lane & 15) * 128;
  const char* ldsAW = ldsb + wm * 17408;  // wm * 136 slots * 128 B
  const int bRdC = (wn * 32 + (lane & 15)) * 128 + (((lane >> 4) ^ (lane & 7)) << 4);

  bf16x8 a[4][2];
  bf16x8 b[2][2];
  f32x4v acc[2][4][2];
  const f32x4v zero = {0.f, 0.f, 0.f, 0.f};
#pragma unroll
  for (int qm = 0; qm < 2; ++qm)
#pragma unroll
    for (int mi = 0; mi < 4; ++mi)
#pragma unroll
      for (int ni = 0; ni < 2; ++ni) acc[qm][mi][ni] = zero;

  // ---- prologue: A panel (k8=0) + B(ts=0 -> buf0) ----
  {
    ST_A3(Ag);
    ST_B(0, Wt);
    VM0; BARR;
  }

  // ---- main loop: 4 k8-pairs x 9 taps, compile-time buffer parity ----
  for (int k2 = 0; k2 < 4; ++k2) {
    {
      const int k8 = 2 * k2;
      TAP9(0)
    }
    {
      const int k8 = 2 * k2 + 1;
      TAP9(1)
    }
  }
  VM0;
  __syncthreads();

  if constexpr (MODE == 1) {
    // bn2 + relu -> padded NHWC bf16
#pragma unroll
    for (int ni = 0; ni < 2; ++ni) {
      const int cog = co0 + wn * 32 + ni * 16 + (lane & 15);
      const float iv = bnp[1024 + cog];
      const float bb = bnp[1536 + cog];
#pragma unroll
      for (int qm = 0; qm < 2; ++qm)
#pragma unroll
        for (int mi = 0; mi < 4; ++mi)
#pragma unroll
          for (int r = 0; r < 4; ++r) {
            const int row = wm * 128 + qm * 64 + mi * 16 + (lane >> 4) * 4 + r;
            const int y = yblk * 8 + (row >> 5), xx = row & 31;
            const float v = fmaxf(fmaf(acc[qm][mi][ni][r], iv, bb), 0.f);
            Hout[((size_t)((n * 34 + y + 1) * 34 + (xx + 1))) * 512 + cog] = f2bf(v);
          }
    }
  } else {
    // LDS transpose -> coalesced f32x4 NCHW + residual (sm: 32 x 264 f32 = 33792 B)
    float* sm = (float*)ldsb;
    const int spat0 = yblk * 256;
#pragma unroll 1
    for (int h = 0; h < 4; ++h) {
      if (wn == h) {
#pragma unroll
        for (int ni = 0; ni < 2; ++ni)
#pragma unroll
          for (int qm = 0; qm < 2; ++qm)
#pragma unroll
            for (int mi = 0; mi < 4; ++mi)
#pragma unroll
              for (int r = 0; r < 4; ++r)
                sm[(ni * 16 + (lane & 15)) * 264 +
                   wm * 128 + qm * 64 + mi * 16 + (lane >> 4) * 4 + r] = acc[qm][mi][ni][r];
      }
      __syncthreads();
#pragma unroll
      for (int j = 0; j < 4; ++j) {
        const int c = j * 512 + t;
        const int cc = c >> 6, px = (c & 63) * 4;
        f32x4v v = *(const f32x4v*)&sm[cc * 264 + px];
        const int cog = co0 + h * 32 + cc;
        const size_t o = ((size_t)(n * 512 + cog)) * 1024 + spat0 + px;
        const f32x4v xr = *(const f32x4v*)(xres + o);
        v = v + xr;
        *(f32x4v*)(outp + o) = v;
      }
      __syncthreads();
    }
  }
}

// ---------------- launcher ----------------
extern "C" void kernel_launch(void* const* d_in, const int* in_sizes, int n_in,
                              void* d_out, int out_size, void* d_ws, size_t ws_size,
                              hipStream_t stream) {
  (void)in_sizes; (void)n_in; (void)out_size; (void)ws_size;
  const float* x    = (const float*)d_in[0];
  const float* bn1g = (const float*)d_in[1];
  const float* bn1b = (const float*)d_in[2];
  const float* bn1m = (const float*)d_in[3];
  const float* bn1v = (const float*)d_in[4];
  const float* w1   = (const float*)d_in[5];
  const float* bn2g = (const float*)d_in[6];
  const float* bn2b = (const float*)d_in[7];
  const float* bn2m = (const float*)d_in[8];
  const float* bn2v = (const float*)d_in[9];
  const float* w2   = (const float*)d_in[10];
  const float* fc1w = (const float*)d_in[11];
  const float* fc1b = (const float*)d_in[12];
  const float* fc2w = (const float*)d_in[13];
  const float* fc2b = (const float*)d_in[14];

  float* out = (float*)d_out;
  float* probeo = out + (size_t)64 * 512 * 32 * 32;

  char* ws = (char*)d_ws;
  unsigned short* Ap  = (unsigned short*)(ws);                 // 75,759,616 B padded NHWC bf16
  unsigned short* Hp  = (unsigned short*)(ws + 75759616);      // 75,759,616 B
  unsigned short* W1t = (unsigned short*)(ws + 151519232);     // 4,718,592 B
  unsigned short* W2t = (unsigned short*)(ws + 156237824);     // 4,718,592 B
  float* partial      = (float*)(ws + 160956416);              // 1,048,576 B
  float* maskp        = (float*)(ws + 162004992);              // 131,072 B
  float* bnp          = (float*)(ws + 162136064);              // 8,192 B

  bnprep<<<1, 512, 0, stream>>>(bn1g, bn1b, bn1m, bn1v, bn2g, bn2b, bn2m, bn2v, bnp);
  ring_zero<<<dim3(33, 64), 256, 0, stream>>>(Ap, Hp);
  wtrans<<<18432, 256, 0, stream>>>(w1, w2, W1t, W2t);
  bn1_relu_stage<<<4096, 256, 0, stream>>>(x, bnp, Ap, partial);
  probe_mask<<<64, 256, 0, stream>>>(partial, fc1w, fc1b, fc2w, fc2b, maskp, probeo);
  apply_mask<<<dim3(289, 64), 256, 0, stream>>>(Ap, maskp);
  conv256<1><<<1024, 512, 0, stream>>>(Ap, W1t, bnp, Hp, nullptr, nullptr);
  conv256<2><<<1024, 512, 0, stream>>>(Hp, W2t, bnp, nullptr, x, out);
}

// Round 6
// 578.359 us; speedup vs baseline: 1.4354x; 1.4354x over previous
//
#include <hip/hip_runtime.h>
#include <stdint.h>

typedef __bf16 bf16x8 __attribute__((ext_vector_type(8)));
typedef float f32x4v __attribute__((ext_vector_type(4)));

typedef __attribute__((address_space(1))) const void gconst_t;
typedef __attribute__((address_space(3))) void lds_t;

// global -> LDS direct copy, 16 B per lane. LDS dest = wave-uniform base + lane*16.
#define GLL16(gp, sp) __builtin_amdgcn_global_load_lds((gconst_t*)(uintptr_t)(gp), (lds_t*)(uintptr_t)(sp), 16, 0, 0)

__device__ __forceinline__ unsigned short f2bf(float f) {
  unsigned int u = __float_as_uint(f);
  u = (u + 0x7FFFu + ((u >> 16) & 1u)) >> 16;
  return (unsigned short)u;
}
__device__ __forceinline__ float bf2f(unsigned int b) {
  return __uint_as_float(b << 16);
}

// ---------------- sizes ----------------
// x: (64,512,32,32) f32. padded NHWC: [n][34][34][512] bf16
#define SPP 1156  // 34*34

// ---------------- bn param prep ----------------
__global__ __launch_bounds__(512) void bnprep(
    const float* __restrict__ g1, const float* __restrict__ b1,
    const float* __restrict__ m1, const float* __restrict__ v1,
    const float* __restrict__ g2, const float* __restrict__ b2,
    const float* __restrict__ m2, const float* __restrict__ v2,
    float* __restrict__ bnp) {
  int t = threadIdx.x;
  float i1 = g1[t] * rsqrtf(v1[t] + 1e-5f);
  bnp[t] = i1;
  bnp[512 + t] = b1[t] - m1[t] * i1;
  float i2 = g2[t] * rsqrtf(v2[t] + 1e-5f);
  bnp[1024 + t] = i2;
  bnp[1536 + t] = b2[t] - m2[t] * i2;
}

// ---------------- pad-ring zero for Ap and Hp (interiors are fully overwritten) ----------------
__global__ __launch_bounds__(256) void ring_zero(unsigned short* __restrict__ Ap,
                                                 unsigned short* __restrict__ Hp) {
  const int n = blockIdx.y;
  const int p = blockIdx.x * 4 + (threadIdx.x >> 6);  // 0..131 ring pixel
  const int lane = threadIdx.x & 63;
  int y, x;
  if (p < 34) { y = 0; x = p; }
  else if (p < 68) { y = 33; x = p - 34; }
  else if (p < 100) { y = p - 67; x = 0; }
  else { y = p - 99; x = 33; }
  const uint4 z = {0u, 0u, 0u, 0u};
  const size_t off = ((size_t)((n * 34 + y) * 34 + x)) * 512 + lane * 8;
  *(uint4*)(Ap + off) = z;
  *(uint4*)(Hp + off) = z;
}

// ---------------- weight transform: w[co][ci][dy][dx] f32 -> wt[tap][co][ci] bf16 ----------------
__global__ __launch_bounds__(256) void wtrans(const float* __restrict__ w1, const float* __restrict__ w2,
                                              unsigned short* __restrict__ w1t, unsigned short* __restrict__ w2t) {
  unsigned e = blockIdx.x * 256u + threadIdx.x;
  if (e >= 4718592u) return;
  const float* w = (e < 2359296u) ? w1 : w2;
  unsigned short* o = (e < 2359296u) ? w1t : w2t;
  unsigned r = (e < 2359296u) ? e : (e - 2359296u);
  unsigned ci = r & 511u, co = (r >> 9) & 511u, tt = r >> 18;
  o[r] = f2bf(w[(co * 512u + ci) * 9u + tt]);
}

// ---------------- bn1+relu, write padded NHWC bf16, per-(n,ci,yblk) partial sums ----------------
__global__ __launch_bounds__(256) void bn1_relu_stage(const float* __restrict__ x, const float* __restrict__ bnp,
                                                      unsigned short* __restrict__ Ap, float* __restrict__ partial) {
  int bid = blockIdx.x;
  int n = bid >> 6, ciblk = (bid >> 3) & 7, yblk = bid & 7;
  int ci0 = ciblk * 64, y0 = yblk * 4;
  int t = threadIdx.x;
  __shared__ __align__(16) float vals[64 * 128];
  __shared__ float ivs[64], bbs[64];
  if (t < 64) { ivs[t] = bnp[ci0 + t]; bbs[t] = bnp[512 + ci0 + t]; }
  __syncthreads();
#pragma unroll
  for (int i = 0; i < 8; ++i) {
    int f4 = i * 256 + t;
    int cil = f4 >> 5, xq = f4 & 31;
    const float* src = x + ((size_t)(n * 512 + ci0 + cil)) * 1024 + y0 * 32 + xq * 4;
    f32x4v v = *(const f32x4v*)src;
    float iv = ivs[cil], bb = bbs[cil];
    f32x4v r;
    r[0] = fmaxf(fmaf(v[0], iv, bb), 0.f);
    r[1] = fmaxf(fmaf(v[1], iv, bb), 0.f);
    r[2] = fmaxf(fmaf(v[2], iv, bb), 0.f);
    r[3] = fmaxf(fmaf(v[3], iv, bb), 0.f);
    *(f32x4v*)&vals[cil * 128 + xq * 4] = r;
  }
  __syncthreads();
  // partial sums per ci (deterministic)
  {
    int cil = t >> 2, q = t & 3;
    float s = 0.f;
#pragma unroll
    for (int j = 0; j < 32; ++j) s += vals[cil * 128 + q * 32 + j];
    s += __shfl_xor(s, 1);
    s += __shfl_xor(s, 2);
    if (q == 0) partial[((size_t)n * 512 + ci0 + cil) * 8 + yblk] = s;
  }
  // transpose to padded NHWC bf16
  {
    int yx = t >> 1, half = t & 1;
    int y = y0 + (yx >> 5), xx = yx & 31;
    unsigned short* dp = Ap + ((size_t)((n * 34 + y + 1) * 34 + (xx + 1))) * 512 + ci0 + half * 32;
    unsigned wrd[16];
#pragma unroll
    for (int j = 0; j < 16; ++j) {
      unsigned lo = f2bf(vals[(half * 32 + 2 * j) * 128 + yx]);
      unsigned hi = f2bf(vals[(half * 32 + 2 * j + 1) * 128 + yx]);
      wrd[j] = lo | (hi << 16);
    }
#pragma unroll
    for (int k = 0; k < 4; ++k) {
      uint4 u;
      u.x = wrd[k * 4]; u.y = wrd[k * 4 + 1]; u.z = wrd[k * 4 + 2]; u.w = wrd[k * 4 + 3];
      *(uint4*)(dp + k * 8) = u;
    }
  }
}

// ---------------- probe + analytic mask; writes pred_probe ----------------
__global__ __launch_bounds__(256) void probe_mask(const float* __restrict__ partial,
                                                  const float* __restrict__ fc1w, const float* __restrict__ fc1b,
                                                  const float* __restrict__ fc2w, const float* __restrict__ fc2b,
                                                  float* __restrict__ maskp, float* __restrict__ probeout) {
  int n = blockIdx.x, t = threadIdx.x;
  int lane = t & 63, wv = t >> 6;
  __shared__ float gl[512], sl[512], zl[240], hl[240], dzl[240], logl[10], red[4];
  __shared__ int idx2[2];
  for (int c = t; c < 512; c += 256) {
    const float* pp = partial + ((size_t)n * 512 + c) * 8;
    float s = 0.f;
#pragma unroll
    for (int j = 0; j < 8; ++j) s += pp[j];
    gl[c] = s * (1.f / 1024.f);
  }
  __syncthreads();
  if (t < 240) {
    float z = fc1b[t];
    const float* wr = fc1w + t * 512;
    for (int c = 0; c < 512; ++c) z = fmaf(gl[c], wr[c], z);
    zl[t] = z;
    float u = 5.f * z;
    float sp = (u > 20.f) ? u : log1pf(expf(u));
    hl[t] = sp * 0.2f;
  }
  __syncthreads();
  if (t < 10) {
    float L = fc2b[t];
    const float* wr = fc2w + t * 240;
    for (int h = 0; h < 240; ++h) L = fmaf(hl[h], wr[h], L);
    logl[t] = L;
    probeout[n * 10 + t] = L;
  }
  __syncthreads();
  if (t == 0) {
    float b1v = -1e30f, b2v = -1e30f; int i1 = 0, i2 = 0;
    for (int j = 0; j < 10; ++j) {
      float v = logl[j];
      if (v > b1v) { b2v = b1v; i2 = i1; b1v = v; i1 = j; }
      else if (v > b2v) { b2v = v; i2 = j; }
    }
    idx2[0] = i1; idx2[1] = i2;
  }
  __syncthreads();
  if (t < 240) {
    float dh = fc2w[idx2[0] * 240 + t] + fc2w[idx2[1] * 240 + t];
    float u = 5.f * zl[t];
    float sg = 1.f / (1.f + expf(-u));
    dzl[t] = dh * sg;
  }
  __syncthreads();
  for (int c = t; c < 512; c += 256) {
    float s = 0.f;
    for (int h = 0; h < 240; ++h) s = fmaf(dzl[h], fc1w[h * 512 + c], s);
    sl[c] = s;
  }
  __syncthreads();
  float m = fmaxf(sl[t], sl[t + 256]);
#pragma unroll
  for (int o = 32; o > 0; o >>= 1) m = fmaxf(m, __shfl_xor(m, o));
  if (lane == 0) red[wv] = m;
  __syncthreads();
  float mx = fmaxf(fmaxf(red[0], red[1]), fmaxf(red[2], red[3]));
  float e0 = expf(sl[t] - mx), e1 = expf(sl[t + 256] - mx);
  float sum = e0 + e1;
#pragma unroll
  for (int o = 32; o > 0; o >>= 1) sum += __shfl_xor(sum, o);
  __syncthreads();
  if (lane == 0) red[wv] = sum;
  __syncthreads();
  float inv = 2.f / (red[0] + red[1] + red[2] + red[3]);
  maskp[(size_t)n * 512 + t] = e0 * inv;
  maskp[(size_t)n * 512 + t + 256] = e1 * inv;
}

// ---------------- in-place mask multiply on padded NHWC bf16 ----------------
__global__ __launch_bounds__(256) void apply_mask(unsigned short* __restrict__ Ap, const float* __restrict__ maskp) {
  int n = blockIdx.y;
  size_t off = (size_t)n * (SPP * 512) + (size_t)blockIdx.x * 2048 + threadIdx.x * 8;
  int ci0 = (int)(threadIdx.x * 8) & 511;
  uint4 v = *(uint4*)(Ap + off);
  const float* mp = maskp + n * 512 + ci0;
  unsigned r0, r1;
  r0 = f2bf(bf2f(v.x & 0xFFFFu) * mp[0]); r1 = f2bf(bf2f(v.x >> 16) * mp[1]); v.x = r0 | (r1 << 16);
  r0 = f2bf(bf2f(v.y & 0xFFFFu) * mp[2]); r1 = f2bf(bf2f(v.y >> 16) * mp[3]); v.y = r0 | (r1 << 16);
  r0 = f2bf(bf2f(v.z & 0xFFFFu) * mp[4]); r1 = f2bf(bf2f(v.z >> 16) * mp[5]); v.z = r0 | (r1 << 16);
  r0 = f2bf(bf2f(v.w & 0xFFFFu) * mp[6]); r1 = f2bf(bf2f(v.w >> 16) * mp[7]); v.w = r0 | (r1 << 16);
  *(uint4*)(Ap + off) = v;
}

// ======== 256x128 implicit-GEMM conv, tap-reuse A panel, 2 blocks/CU (v4) ========
// BM=256 px, BN=128 co, BK=64. 8 waves (2M x 4N: each wave 128px x 32co), 512 thr.
// LDS = A panel 48K [384 slots][128B] + B dbuf 2x16K = 81920 B -> 2 blocks/CU.
// Occupancy pinned with amdgpu_waves_per_eu(4,4): hard 128-VGPR target (R5's
// launch_bounds(512,4) let the allocator chase 8 waves/EU at 64 VGPR -> spills).
// ROW-STRIDE FIX vs R4/R5: output frag (QM, mi=2H+m) covers pixel row ly=2QM+H,
// so A reads slot (2QM+H+dy)*34 + dx + (m?16:0) -> +H*34 slots (+4352 B), NOT
// +8704. R4/R5 read ly+2 for H=1 (absmax 0.031->0.070, masked by tiny conv path).
// Swizzle (both-sides, rule 21): LDS chunk q of slot s holds global chunk q^(s&7)
// (linear GLL dest + permuted source); reads XOR back, second k-chunk = addr^64.
// Tap-step (single barrier; cross-block TLP hides drains):
//   {ST_B(buf^1, tile ts+1) issue; RD_B(buf); 4x[RD_A2 || 8 MFMA]; VM0; LGKM0; BARR}
// tap8: last A-reads drained (LGKM0+BARR) before ST_A3 overwrites panel; final
// VM0 covers A-panel + B GLLs before next k8 reads either.
#define LT(M) ((l4 ^ (((M) + l7) & 7)) << 4)

#define RD_A2(QM, H, TAP) do {                                                \
  const int _S0 = ((QM) * 2 + (H) + (TAP) / 3) * 34 + (TAP) % 3;              \
  const int _l = l15x128 + LT(_S0 & 7);                                       \
  const char* _p = ldsAW + _S0 * 128;                                         \
  a2[0][0] = *(const bf16x8*)(_p + _l);                                       \
  a2[0][1] = *(const bf16x8*)(_p + (_l ^ 64));                                \
  a2[1][0] = *(const bf16x8*)(_p + 2048 + _l);                                \
  a2[1][1] = *(const bf16x8*)(_p + 2048 + (_l ^ 64));                         \
} while (0)

#define RD_B(BUF) do {                                                        \
  const char* _pb = ldsb + 49152 + (BUF) * 16384;                             \
  b[0][0] = *(const bf16x8*)(_pb + bRdC);                                     \
  b[0][1] = *(const bf16x8*)(_pb + (bRdC ^ 64));                              \
  b[1][0] = *(const bf16x8*)(_pb + 2048 + bRdC);                              \
  b[1][1] = *(const bf16x8*)(_pb + 2048 + (bRdC ^ 64));                       \
} while (0)

#define ST_B(BUF, BP) do {                                                    \
  GLL16((BP) + bOff0,         ldsb + 49152 + (BUF) * 16384 + tb);             \
  GLL16((BP) + bOff0 + 32768, ldsb + 49152 + (BUF) * 16384 + 8192 + tb);      \
} while (0)

#define ST_A3(AP) do {                                                        \
  GLL16((AP) + aOff0,          ldsb + tb);                                    \
  GLL16((AP) + aOff0 + 32768,  ldsb + 8192 + tb);                             \
  GLL16((AP) + aOff0 + 65536,  ldsb + 16384 + tb);                            \
  GLL16((AP) + aOff0 + 98304,  ldsb + 24576 + tb);                            \
  GLL16((AP) + aOff0 + 131072, ldsb + 32768 + tb);                            \
  GLL16((AP) + aOff0 + 163840, ldsb + 40960 + tb);                            \
} while (0)

#define MFMA8(QM, H) do {                                                     \
  _Pragma("unroll") for (int m = 0; m < 2; ++m)                               \
  _Pragma("unroll") for (int n2 = 0; n2 < 2; ++n2) {                          \
    acc[QM][(H) * 2 + m][n2] = __builtin_amdgcn_mfma_f32_16x16x32_bf16(       \
        a2[m][0], b[n2][0], acc[QM][(H) * 2 + m][n2], 0, 0, 0);               \
    acc[QM][(H) * 2 + m][n2] = __builtin_amdgcn_mfma_f32_16x16x32_bf16(       \
        a2[m][1], b[n2][1], acc[QM][(H) * 2 + m][n2], 0, 0, 0); }             \
} while (0)

#define BARR __builtin_amdgcn_s_barrier()
#define LGKM0 do { asm volatile("s_waitcnt lgkmcnt(0)" ::: "memory");         \
                   __builtin_amdgcn_sched_barrier(0); } while (0)
#define VM0 asm volatile("s_waitcnt vmcnt(0)" ::: "memory")
#define PRIO1 __builtin_amdgcn_s_setprio(1)
#define PRIO0 __builtin_amdgcn_s_setprio(0)

#define TAPSTEP(TAP, PAR) do {                                                \
  const unsigned short* _bpn;                                                 \
  if ((TAP) < 8) _bpn = Wt + (size_t)((TAP) + 1) * 262144 + k8 * 64;          \
  else           _bpn = (k8 < 7) ? Wt + (size_t)(k8 + 1) * 64                 \
                                 : Wt + (size_t)8 * 262144 + 7 * 64;          \
  ST_B((((TAP) + (PAR)) & 1) ^ 1, _bpn);                                      \
  RD_B(((TAP) + (PAR)) & 1);                                                  \
  RD_A2(0, 0, TAP); PRIO1; MFMA8(0, 0); PRIO0;                                \
  RD_A2(0, 1, TAP); PRIO1; MFMA8(0, 1); PRIO0;                                \
  RD_A2(1, 0, TAP); PRIO1; MFMA8(1, 0); PRIO0;                                \
  if ((TAP) < 8) {                                                            \
    RD_A2(1, 1, TAP); PRIO1; MFMA8(1, 1); PRIO0;                              \
    VM0; LGKM0; BARR;                                                         \
  } else {                                                                    \
    RD_A2(1, 1, TAP);                                                         \
    LGKM0; BARR;                                                              \
    if (k8 < 7) { ST_A3(Ag + (size_t)(k8 + 1) * 64); }                        \
    PRIO1; MFMA8(1, 1); PRIO0;                                                \
    VM0; BARR;                                                                \
  }                                                                           \
} while (0)

#define TAP9(PAR)                                                             \
  TAPSTEP(0, PAR); TAPSTEP(1, PAR); TAPSTEP(2, PAR);                          \
  TAPSTEP(3, PAR); TAPSTEP(4, PAR); TAPSTEP(5, PAR);                          \
  TAPSTEP(6, PAR); TAPSTEP(7, PAR); TAPSTEP(8, PAR);

template <int MODE>
__global__ __attribute__((amdgpu_flat_work_group_size(512, 512), amdgpu_waves_per_eu(4, 4)))
void conv256(
    const unsigned short* __restrict__ Ain,
    const unsigned short* __restrict__ Wt,
    const float* __restrict__ bnp,
    unsigned short* __restrict__ Hout,
    const float* __restrict__ xres,
    float* __restrict__ outp) {
  __shared__ __align__(16) char ldsb[81920];  // A panel 48K + B dbuf 32K

  const int t = threadIdx.x;
  const int lane = t & 63;
  const int wv = t >> 6;
  const int wm = wv >> 2;  // 0..1: M-half (128 px)
  const int wn = wv & 3;   // 0..3: N quarter (32 co)

  const int bid = blockIdx.x;
  const int logical = (bid & 7) * 128 + (bid >> 3);  // bijective: 1024 % 8 == 0
  const int nt = logical & 3, mt = logical >> 2;
  const int n = mt >> 2, yblk = mt & 3;
  const int co0 = nt * 128;

  const unsigned short* Ag = Ain + (size_t)n * (SPP * 512);

  // round-invariant source swizzle chunk: kq = (t&7) ^ ((t>>3)&7)
  const int kq8 = ((t & 7) ^ ((t >> 3) & 7)) * 8;
  const int aOff0 = (yblk * 272 + (t >> 3)) * 512 + kq8;
  const int bOff0 = (co0 + (t >> 3)) * 512 + kq8;
  const int tb = t * 16;
  const int l4 = lane >> 4, l7 = lane & 7;
  const int l15x128 = (lane & 15) * 128;
  const char* ldsAW = ldsb + wm * 17408;  // wm * 136 slots * 128 B (4 rows)
  const int bRdC = (wn * 32 + (lane & 15)) * 128 + (((lane >> 4) ^ (lane & 7)) << 4);

  bf16x8 a2[2][2];
  bf16x8 b[2][2];
  f32x4v acc[2][4][2];
  const f32x4v zero = {0.f, 0.f, 0.f, 0.f};
#pragma unroll
  for (int qm = 0; qm < 2; ++qm)
#pragma unroll
    for (int mi = 0; mi < 4; ++mi)
#pragma unroll
      for (int ni = 0; ni < 2; ++ni) acc[qm][mi][ni] = zero;

  // ---- prologue: A panel (k8=0) + B(ts=0 -> buf0) ----
  {
    ST_A3(Ag);
    ST_B(0, Wt);
    VM0; BARR;
  }

  // ---- main loop: 4 k8-pairs x 9 taps, compile-time buffer parity ----
  for (int k2 = 0; k2 < 4; ++k2) {
    {
      const int k8 = 2 * k2;
      TAP9(0)
    }
    {
      const int k8 = 2 * k2 + 1;
      TAP9(1)
    }
  }
  VM0;
  __syncthreads();

  if constexpr (MODE == 1) {
    // bn2 + relu -> padded NHWC bf16
#pragma unroll
    for (int ni = 0; ni < 2; ++ni) {
      const int cog = co0 + wn * 32 + ni * 16 + (lane & 15);
      const float iv = bnp[1024 + cog];
      const float bb = bnp[1536 + cog];
#pragma unroll
      for (int qm = 0; qm < 2; ++qm)
#pragma unroll
        for (int mi = 0; mi < 4; ++mi)
#pragma unroll
          for (int r = 0; r < 4; ++r) {
            const int row = wm * 128 + qm * 64 + mi * 16 + (lane >> 4) * 4 + r;
            const int y = yblk * 8 + (row >> 5), xx = row & 31;
            const float v = fmaxf(fmaf(acc[qm][mi][ni][r], iv, bb), 0.f);
            Hout[((size_t)((n * 34 + y + 1) * 34 + (xx + 1))) * 512 + cog] = f2bf(v);
          }
    }
  } else {
    // LDS transpose -> coalesced f32x4 NCHW + residual (sm: 32 x 264 f32 = 33792 B)
    float* sm = (float*)ldsb;
    const int spat0 = yblk * 256;
#pragma unroll 1
    for (int h = 0; h < 4; ++h) {
      if (wn == h) {
#pragma unroll
        for (int ni = 0; ni < 2; ++ni)
#pragma unroll
          for (int qm = 0; qm < 2; ++qm)
#pragma unroll
            for (int mi = 0; mi < 4; ++mi)
#pragma unroll
              for (int r = 0; r < 4; ++r)
                sm[(ni * 16 + (lane & 15)) * 264 +
                   wm * 128 + qm * 64 + mi * 16 + (lane >> 4) * 4 + r] = acc[qm][mi][ni][r];
      }
      __syncthreads();
#pragma unroll
      for (int j = 0; j < 4; ++j) {
        const int c = j * 512 + t;
        const int cc = c >> 6, px = (c & 63) * 4;
        f32x4v v = *(const f32x4v*)&sm[cc * 264 + px];
        const int cog = co0 + h * 32 + cc;
        const size_t o = ((size_t)(n * 512 + cog)) * 1024 + spat0 + px;
        const f32x4v xr = *(const f32x4v*)(xres + o);
        v = v + xr;
        *(f32x4v*)(outp + o) = v;
      }
      __syncthreads();
    }
  }
}

// ---------------- launcher ----------------
extern "C" void kernel_launch(void* const* d_in, const int* in_sizes, int n_in,
                              void* d_out, int out_size, void* d_ws, size_t ws_size,
                              hipStream_t stream) {
  (void)in_sizes; (void)n_in; (void)out_size; (void)ws_size;
  const float* x    = (const float*)d_in[0];
  const float* bn1g = (const float*)d_in[1];
  const float* bn1b = (const float*)d_in[2];
  const float* bn1m = (const float*)d_in[3];
  const float* bn1v = (const float*)d_in[4];
  const float* w1   = (const float*)d_in[5];
  const float* bn2g = (const float*)d_in[6];
  const float* bn2b = (const float*)d_in[7];
  const float* bn2m = (const float*)d_in[8];
  const float* bn2v = (const float*)d_in[9];
  const float* w2   = (const float*)d_in[10];
  const float* fc1w = (const float*)d_in[11];
  const float* fc1b = (const float*)d_in[12];
  const float* fc2w = (const float*)d_in[13];
  const float* fc2b = (const float*)d_in[14];

  float* out = (float*)d_out;
  float* probeo = out + (size_t)64 * 512 * 32 * 32;

  char* ws = (char*)d_ws;
  unsigned short* Ap  = (unsigned short*)(ws);                 // 75,759,616 B padded NHWC bf16
  unsigned short* Hp  = (unsigned short*)(ws + 75759616);      // 75,759,616 B
  unsigned short* W1t = (unsigned short*)(ws + 151519232);     // 4,718,592 B
  unsigned short* W2t = (unsigned short*)(ws + 156237824);     // 4,718,592 B
  float* partial      = (float*)(ws + 160956416);              // 1,048,576 B
  float* maskp        = (float*)(ws + 162004992);              // 131,072 B
  float* bnp          = (float*)(ws + 162136064);              // 8,192 B

  bnprep<<<1, 512, 0, stream>>>(bn1g, bn1b, bn1m, bn1v, bn2g, bn2b, bn2m, bn2v, bnp);
  ring_zero<<<dim3(33, 64), 256, 0, stream>>>(Ap, Hp);
  wtrans<<<18432, 256, 0, stream>>>(w1, w2, W1t, W2t);
  bn1_relu_stage<<<4096, 256, 0, stream>>>(x, bnp, Ap, partial);
  probe_mask<<<64, 256, 0, stream>>>(partial, fc1w, fc1b, fc2w, fc2b, maskp, probeo);
  apply_mask<<<dim3(289, 64), 256, 0, stream>>>(Ap, maskp);
  conv256<1><<<1024, 512, 0, stream>>>(Ap, W1t, bnp, Hp, nullptr, nullptr);
  conv256<2><<<1024, 512, 0, stream>>>(Hp, W2t, bnp, nullptr, x, out);
}